// Round 5
// baseline (687.233 us; speedup 1.0000x reference)
//
#include <hip/hip_runtime.h>

// LateralInhibition: out = inputs * ((inputs @ w1 + b) > 0), w1 = w with zero diag.
// inputs: [M=32768, 512] fp32 row-major; w: [512,512] fp32 (w[k][n]).
//
// R5: R4's outer-product shape (thread = one row m, BN=64 cols; W rows are
// wave-uniform -> SGPRs via s_load, dual-issued with VALU; acc[64] in VGPRs;
// k-sequential fmaf per (m,n) -> bit-exact vs np, absmax 0.0) BUT with the A
// feed fixed: R4 read A per-lane with 2KB lane stride (64 lines/instr, L1
// thrash -> ~800cyc stalls, VALUBusy 44%). Now A tiles (256 rows x BK=32) are
// staged into LDS with coalesced global loads + register prefetch of the next
// tile; each thread reads its own LDS row via ds_read_b128 (stride 36 dwords
// ~= conflict-free; ~3 cyc/k vs 128 cyc FMA/k).

#define NUMD 512
#define BN 64     // columns per thread (acc VGPRs)
#define ROWS 256  // rows per block = blockDim.x
#define BK 32     // k-tile
#define LDK 36    // padded LDS row stride (dwords); (36/4)=9 odd -> clean b128 banks

__global__ __launch_bounds__(256) void li_prep(const float* __restrict__ W,
                                               float* __restrict__ Wz) {
    const int idx = (blockIdx.x * 256 + threadIdx.x) * 4;
    const int row = idx >> 9;
    const int col = idx & (NUMD - 1);
    float4 v = *(const float4*)(W + idx);
    const int d = row - col;
    if (d >= 0 && d < 4) ((float*)&v)[d] = 0.0f;
    *(float4*)(Wz + idx) = v;
}

__global__ __launch_bounds__(256) void li_main(const float* __restrict__ A,
                                               const float* __restrict__ Wz,
                                               const float* __restrict__ bias,
                                               float* __restrict__ out, int M) {
    __shared__ __align__(16) float As[ROWS][LDK];  // 36 KB

    const int t  = threadIdx.x;
    const int m  = blockIdx.x * ROWS + t;
    const int n0 = blockIdx.y * BN;
    const float* __restrict__ Arow = A + (size_t)m * NUMD;

    // staging map: 2048 float4s per tile; thread t does f4 = t + 256*i, i=0..7
    // row = f4>>3 (8 float4 per row), c4 = f4&7  -> consecutive lanes hit
    // consecutive 16B of the same row (coalesced).
    const int srow = t >> 3;        // base row for i=0
    const int sc4  = t & 7;         // float4 column

    float acc[BN];
#pragma unroll
    for (int n = 0; n < BN; ++n) acc[n] = 0.0f;

    // prefetch tile 0
    float4 pf[8];
#pragma unroll
    for (int i = 0; i < 8; ++i) {
        const int r = srow + 32 * i;
        pf[i] = *(const float4*)(A + (size_t)(blockIdx.x * ROWS + r) * NUMD + sc4 * 4);
    }

    const int NT = NUMD / BK; // 16
    for (int kt = 0; kt < NT; ++kt) {
        const int k0 = kt * BK;

        // stage prefetched tile into LDS
#pragma unroll
        for (int i = 0; i < 8; ++i)
            *(float4*)&As[srow + 32 * i][sc4 * 4] = pf[i];
        __syncthreads();

        // issue global prefetch of next tile (consumed after next barrier)
        if (kt + 1 < NT) {
#pragma unroll
            for (int i = 0; i < 8; ++i) {
                const int r = srow + 32 * i;
                pf[i] = *(const float4*)(A + (size_t)(blockIdx.x * ROWS + r) * NUMD
                                         + k0 + BK + sc4 * 4);
            }
        }

        // compute BK k-steps; A from own LDS row, W from SGPRs (uniform s_load)
#pragma unroll
        for (int k4 = 0; k4 < BK / 4; ++k4) {
            float4 av = *(const float4*)&As[t][k4 * 4];
            const float a4[4] = {av.x, av.y, av.z, av.w};
#pragma unroll
            for (int kk = 0; kk < 4; ++kk) {
                const float a = a4[kk];
                const float* __restrict__ wr = Wz + (size_t)(k0 + k4 * 4 + kk) * NUMD + n0;
#pragma unroll
                for (int n = 0; n < BN; ++n)
                    acc[n] = fmaf(a, wr[n], acc[n]);
            }
        }
        __syncthreads();
    }

    // epilogue: out[m][n] = in[m][n] * ((acc + b[n]) > 0)
    const float* __restrict__ xin = Arow + n0;
    float* __restrict__ orow = out + (size_t)m * NUMD + n0;
#pragma unroll
    for (int c = 0; c < BN; c += 4) {
        float4 x = *(const float4*)(xin + c);
        float4 o;
        o.x = ((acc[c + 0] + bias[n0 + c + 0]) > 0.0f) ? x.x : 0.0f;
        o.y = ((acc[c + 1] + bias[n0 + c + 1]) > 0.0f) ? x.y : 0.0f;
        o.z = ((acc[c + 2] + bias[n0 + c + 2]) > 0.0f) ? x.z : 0.0f;
        o.w = ((acc[c + 3] + bias[n0 + c + 3]) > 0.0f) ? x.w : 0.0f;
        *(float4*)(orow + c) = o;
    }
}

extern "C" void kernel_launch(void* const* d_in, const int* in_sizes, int n_in,
                              void* d_out, int out_size, void* d_ws, size_t ws_size,
                              hipStream_t stream) {
    const float* A    = (const float*)d_in[0]; // inputs [8*4096, 512]
    const float* W    = (const float*)d_in[1]; // w [512, 512]
    const float* bias = (const float*)d_in[2]; // b [512]
    float* out        = (float*)d_out;
    float* Wz         = (float*)d_ws;          // 1 MiB scratch: diag-zeroed W

    const int M = in_sizes[0] / NUMD; // 32768

    li_prep<<<(NUMD * NUMD / 4 + 255) / 256, 256, 0, stream>>>(W, Wz);
    dim3 grid(M / ROWS, NUMD / BN); // (128, 8) = 1024 blocks
    li_main<<<grid, 256, 0, stream>>>(A, Wz, bias, out, M);
}

// Round 6
// 334.665 us; speedup vs baseline: 2.0535x; 2.0535x over previous
//
#include <hip/hip_runtime.h>

// LateralInhibition: out = inputs * ((inputs @ w1 + b) > 0), w1 = w with zero diag.
// inputs: [M=32768, 512] fp32 row-major; w: [512,512] fp32 (w[k][n]).
//
// R6: R2's two-barrier LDS-tile structure (its 58% VALUBusy matched the
// delivered-bandwidth ceiling (TM+TN)/(TM*TN)=0.25 -> 67%), scaled to
// TM=8 x TN=16 (ratio 0.1875 -> 89% ceiling). B fragments at stride 16 would
// 4-way conflict, so Bs uses a skewed layout col(n) = n + (n>>5)*4: fragment
// bases hit 8 distinct banks; 16-float frags never cross a pad. A path is
// byte-identical to R2. NO s_load in the hot loop (R5 lesson: ds_read+s_load
// share lgkmcnt, complete out-of-order -> conservative drains serialize).
// k-sequential fp32 fmaf per (m,n) -> bit-identical to np/BLAS, absmax 0.0.

#define NUMD 512
#define BM 128
#define BN 256
#define BK 16
#define TM 8
#define TN 16
#define LDA 132    // As row stride (dwords): 128+4 pad (R2-proven)
#define LDBP 288   // Bs physical row stride (dwords): 256 data + 8 pads x4

__global__ __launch_bounds__(256) void li_gemm_gate(
    const float* __restrict__ A,    // [M, 512]
    const float* __restrict__ W,    // [512, 512]
    const float* __restrict__ bias, // [512]
    float* __restrict__ out,        // [M, 512]
    int M)
{
    __shared__ __align__(16) float As[BK][LDA];   // transposed: As[k][m]   8.4 KB
    __shared__ __align__(16) float Bs[BK][LDBP];  // skewed:     Bs[k][col] 18.4 KB

    const int tid  = threadIdx.x;
    const int lane = tid & 63;
    const int wave = tid >> 6;
    const int mg   = (wave >> 1) * 8 + (lane >> 3);  // 0..15 m-group (x8 rows)
    const int ng   = (wave & 1) * 8 + (lane & 7);    // 0..15 n-group (x16 cols)

    const int m0 = blockIdx.x * BM;
    const int n0 = blockIdx.y * BN;

    // --- A staging map (identical to R2) ---
    const int arow = tid >> 1;         // 0..127
    const int acol = (tid & 1) * 8;    // 0 or 8
    // --- B staging map: thread loads 4x float4, rows brow+4r, f4-col bc4 ---
    const int brow = tid >> 6;         // 0..3
    const int bc4  = tid & 63;         // 0..63
    const int bcol = bc4 * 4;          // 0..252
    const int bphys = bcol + ((bcol >> 5) << 2);   // skewed store col
    const int bfc   = ng * 16 + ((ng >> 1) << 2);  // skewed frag base col

    const float* Aptr = A + (size_t)(m0 + arow) * NUMD + acol;
    const float* Wptr = W + (size_t)brow * NUMD + n0 + bcol;

    float acc[TM][TN];
#pragma unroll
    for (int i = 0; i < TM; ++i)
#pragma unroll
        for (int j = 0; j < TN; ++j) acc[i][j] = 0.0f;

    // prefetch tile 0
    float4 ar0 = *(const float4*)(Aptr);
    float4 ar1 = *(const float4*)(Aptr + 4);
    float4 bw[4];
#pragma unroll
    for (int r = 0; r < 4; ++r)
        bw[r] = *(const float4*)(Wptr + (size_t)(4 * r) * NUMD);

    const int NT = NUMD / BK; // 32
    for (int kt = 0; kt < NT; ++kt) {
        const int kk = kt * BK;

        // zero diagonal of the staged W f4s: global elem (kk+brow+4r, n0+bcol+d)
#pragma unroll
        for (int r = 0; r < 4; ++r) {
            const int d = (kk + brow + 4 * r) - (n0 + bcol);
            if (d >= 0 && d < 4) ((float*)&bw[r])[d] = 0.0f;
        }

        // stage into LDS
#pragma unroll
        for (int j = 0; j < 4; ++j) {
            As[acol + j][arow]     = ((const float*)&ar0)[j];
            As[acol + 4 + j][arow] = ((const float*)&ar1)[j];
        }
#pragma unroll
        for (int r = 0; r < 4; ++r)
            *(float4*)&Bs[brow + 4 * r][bphys] = bw[r];
        __syncthreads();

        // prefetch next tile (in flight across the compute phase)
        if (kt + 1 < NT) {
            Aptr += BK;
            Wptr += (size_t)BK * NUMD;
            ar0 = *(const float4*)(Aptr);
            ar1 = *(const float4*)(Aptr + 4);
#pragma unroll
            for (int r = 0; r < 4; ++r)
                bw[r] = *(const float4*)(Wptr + (size_t)(4 * r) * NUMD);
        }

        // compute BK k-steps (k sequential -> bit-exact accumulation order)
#pragma unroll 8
        for (int k = 0; k < BK; ++k) {
            const float* ap = &As[k][mg * TM];
            const float* bp = &Bs[k][bfc];
            float4 a0 = *(const float4*)(ap);
            float4 a1 = *(const float4*)(ap + 4);
            float4 b0 = *(const float4*)(bp);
            float4 b1 = *(const float4*)(bp + 4);
            float4 b2 = *(const float4*)(bp + 8);
            float4 b3 = *(const float4*)(bp + 12);
            float a[TM] = {a0.x, a0.y, a0.z, a0.w, a1.x, a1.y, a1.z, a1.w};
            float b[TN] = {b0.x, b0.y, b0.z, b0.w, b1.x, b1.y, b1.z, b1.w,
                           b2.x, b2.y, b2.z, b2.w, b3.x, b3.y, b3.z, b3.w};
#pragma unroll
            for (int i = 0; i < TM; ++i)
#pragma unroll
                for (int j = 0; j < TN; ++j)
                    acc[i][j] = fmaf(a[i], b[j], acc[i][j]);
        }
        __syncthreads();
    }

    // epilogue: out[m][n] = in[m][n] * ((acc + b[n]) > 0)
    float4 bb[4];
#pragma unroll
    for (int c = 0; c < 4; ++c)
        bb[c] = *(const float4*)(bias + n0 + ng * 16 + c * 4);
    const float* bv = (const float*)bb;

#pragma unroll
    for (int i = 0; i < TM; ++i) {
        const int gm = m0 + mg * TM + i;
        const float* xin = A + (size_t)gm * NUMD + n0 + ng * 16;
        float* orow = out + (size_t)gm * NUMD + n0 + ng * 16;
#pragma unroll
        for (int c = 0; c < 4; ++c) {
            float4 x = *(const float4*)(xin + c * 4);
            float4 o;
            o.x = ((acc[i][c * 4 + 0] + bv[c * 4 + 0]) > 0.0f) ? x.x : 0.0f;
            o.y = ((acc[i][c * 4 + 1] + bv[c * 4 + 1]) > 0.0f) ? x.y : 0.0f;
            o.z = ((acc[i][c * 4 + 2] + bv[c * 4 + 2]) > 0.0f) ? x.z : 0.0f;
            o.w = ((acc[i][c * 4 + 3] + bv[c * 4 + 3]) > 0.0f) ? x.w : 0.0f;
            *(float4*)(orow + c * 4) = o;
        }
    }
}

extern "C" void kernel_launch(void* const* d_in, const int* in_sizes, int n_in,
                              void* d_out, int out_size, void* d_ws, size_t ws_size,
                              hipStream_t stream) {
    const float* A    = (const float*)d_in[0]; // inputs [8*4096, 512]
    const float* W    = (const float*)d_in[1]; // w [512, 512]
    const float* bias = (const float*)d_in[2]; // b [512]
    float* out        = (float*)d_out;

    const int M = in_sizes[0] / NUMD; // 32768
    dim3 grid(M / BM, NUMD / BN);     // (256, 2) = 512 blocks = 2/CU
    li_gemm_gate<<<grid, 256, 0, stream>>>(A, W, bias, out, M);
}